// Round 7
// baseline (90.187 us; speedup 1.0000x reference)
//
#include <hip/hip_runtime.h>
#include <hip/hip_bf16.h>

namespace {

constexpr int kB = 4, kF = 64, kN = 4096;
constexpr int kM = kB * kF * kN;  // 1048576 total elements for std()

typedef __attribute__((ext_vector_type(8))) short bf16x8;
typedef __attribute__((ext_vector_type(4))) float f32x4;

__device__ __forceinline__ void wave_red2(float& s, float& q) {
#pragma unroll
  for (int o = 32; o > 0; o >>= 1) {
    s += __shfl_down(s, o, 64);
    q += __shfl_down(q, o, 64);
  }
}

// K1: 1024 blocks x 256 threads, each thread reduces 4 floats (float4 load).
__global__ void k_reduce1(const float* __restrict__ emb, float* __restrict__ part) {
  int t = blockIdx.x * blockDim.x + threadIdx.x;
  float4 v = reinterpret_cast<const float4*>(emb)[t];
  float s = v.x + v.y + v.z + v.w;
  float q = v.x * v.x + v.y * v.y + v.z * v.z + v.w * v.w;
  wave_red2(s, q);
  __shared__ float ls[4], lq[4];
  int lane = threadIdx.x & 63, w = threadIdx.x >> 6;
  if (lane == 0) { ls[w] = s; lq[w] = q; }
  __syncthreads();
  if (threadIdx.x == 0) {
    s = ls[0] + ls[1] + ls[2] + ls[3];
    q = lq[0] + lq[1] + lq[2] + lq[3];
    part[blockIdx.x] = s;
    part[1024 + blockIdx.x] = q;
  }
}

// K2: 256 blocks x 256 threads. Each block folds the 2048 partials itself
// (8 KB, L2-hit) -> inv_std, then converts 64 n-values: thread = (fq, nl).
// coordT[b][n][f] = bf16(emb[b][f][n] * inv_std); sq[b][n] = sum_f coord^2
// (sq from ROUNDED bf16 values so the diagonal of d2 is exactly 0).
__global__ __launch_bounds__(256) void k_convert(const float* __restrict__ emb,
                                                 const float* __restrict__ part,
                                                 unsigned short* __restrict__ coordT,
                                                 float* __restrict__ sq) {
  int t = threadIdx.x;
  // fold partials -> inv_std (redundant per block; reads are L2-resident)
  float s = part[t] + part[t + 256] + part[t + 512] + part[t + 768];
  float q = part[1024 + t] + part[1280 + t] + part[1536 + t] + part[1792 + t];
  wave_red2(s, q);
  __shared__ float ls[4], lq[4];
  __shared__ float s_inv;
  int lane = t & 63, w = t >> 6;
  if (lane == 0) { ls[w] = s; lq[w] = q; }
  __syncthreads();
  if (t == 0) {
    s = ls[0] + ls[1] + ls[2] + ls[3];
    q = lq[0] + lq[1] + lq[2] + lq[3];
    float mean = s / (float)kM;
    float var = (q - s * mean) / (float)(kM - 1);  // Bessel ddof=1
    s_inv = 1.0f / sqrtf(var);
  }
  __syncthreads();
  float inv_std = s_inv;

  int nl = t & 63, fq = t >> 6;           // wave w == fq -> coalesced 256B loads
  int g = blockIdx.x * 64 + nl;           // [0, B*N)
  int b = g >> 12, n = g & 4095;
  const float* src = emb + ((size_t)b * kF + fq * 16) * kN + n;
  alignas(16) unsigned short loc[16];
  float acc = 0.f;
#pragma unroll
  for (int f = 0; f < 16; f++) {
    float v = src[(size_t)f * kN] * inv_std;
    union { __hip_bfloat16 h; unsigned short u; } cv;
    cv.h = __float2bfloat16(v);
    loc[f] = cv.u;
    float vf = __bfloat162float(cv.h);
    acc += vf * vf;
  }
  bf16x8* dst = reinterpret_cast<bf16x8*>(coordT + (size_t)g * kF + fq * 16);
  dst[0] = reinterpret_cast<const bf16x8*>(loc)[0];
  dst[1] = reinterpret_cast<const bf16x8*>(loc)[1];

  __shared__ float pacc[4][64];
  pacc[fq][nl] = acc;
  __syncthreads();
  if (fq == 0) sq[g] = pacc[0][nl] + pacc[1][nl] + pacc[2][nl] + pacc[3][nl];
}

// K3: per batch, out = exp(-max((sq_i + sq_j - 2*coordT·coordT^T),0)/64/2).
// Block tile 128(i) x 64(j), 4 waves, wave tile 64(i) x 32(j).
// Wave tile shrunk from 64x64 (R6) to cut VGPRs (~150) -> 3 blocks/CU
// (12 waves/CU): a store-bound kernel needs more resident waves to keep
// the write queues full. Store pattern identical to R6: TRANSPOSED
// (value (i,j) -> location (j,i); d2 formula is symmetric, verified R4/R6),
// normal cached float4 stores (NT regressed: 99us, defeats L2 combining).
__global__ __launch_bounds__(256, 3) void k_gemm_exp(const unsigned short* __restrict__ coordT,
                                                     const float* __restrict__ sq,
                                                     float* __restrict__ out) {
  int b = blockIdx.z;
  int wid = threadIdx.x >> 6;
  int lane = threadIdx.x & 63;
  int lhi = lane >> 4, llo = lane & 15;
  int i0 = blockIdx.y * 128 + (wid >> 1) * 64;
  int j0 = blockIdx.x * 64 + (wid & 1) * 32;
  const unsigned short* base = coordT + (size_t)b * kN * kF;

  // A fragment: lane holds row (i0+m*16+llo), k = kk*32 + lhi*8 .. +7 (contig short8)
  bf16x8 af[4][2], bfr[2][2];
#pragma unroll
  for (int m = 0; m < 4; m++) {
    const unsigned short* p = base + (size_t)(i0 + m * 16 + llo) * kF + lhi * 8;
    af[m][0] = *reinterpret_cast<const bf16x8*>(p);
    af[m][1] = *reinterpret_cast<const bf16x8*>(p + 32);
  }
#pragma unroll
  for (int n = 0; n < 2; n++) {
    const unsigned short* p = base + (size_t)(j0 + n * 16 + llo) * kF + lhi * 8;
    bfr[n][0] = *reinterpret_cast<const bf16x8*>(p);
    bfr[n][1] = *reinterpret_cast<const bf16x8*>(p + 32);
  }

  f32x4 acc[4][2] = {};
#pragma unroll
  for (int kk = 0; kk < 2; kk++)
#pragma unroll
    for (int m = 0; m < 4; m++)
#pragma unroll
      for (int n = 0; n < 2; n++)
        acc[m][n] = __builtin_amdgcn_mfma_f32_16x16x32_bf16(af[m][kk], bfr[n][kk], acc[m][n], 0, 0, 0);

  const float* sqb = sq + (size_t)b * kN;
  float si[4][4];
#pragma unroll
  for (int m = 0; m < 4; m++) {
    f32x4 tv = *reinterpret_cast<const f32x4*>(&sqb[i0 + m * 16 + lhi * 4]);
    si[m][0] = tv[0]; si[m][1] = tv[1]; si[m][2] = tv[2]; si[m][3] = tv[3];
  }
  float sj[2];
#pragma unroll
  for (int n = 0; n < 2; n++) sj[n] = sqb[j0 + n * 16 + llo];

  // exp(-max(raw,0)/64/2) = exp2(-max(raw,0) * log2(e)/128)
  constexpr float kC = -0.011271055f;  // 1.4426950408889634 / 128
  float* ob = out + (size_t)b * kN * kN;
#pragma unroll
  for (int n = 0; n < 2; n++) {
    float* rp = ob + (size_t)(j0 + n * 16 + llo) * kN + i0 + (lhi << 2);
#pragma unroll
    for (int m = 0; m < 4; m++) {
      f32x4 wv;
#pragma unroll
      for (int r = 0; r < 4; r++) {
        // C/D layout: col = lane&15, row = (lane>>4)*4 + r.
        // Transposed store: memory row = j0+n*16+llo, col = i0+m*16+lhi*4+r.
        float raw = si[m][r] + sj[n] - 2.0f * acc[m][n][r];
        raw = fmaxf(raw, 0.0f);
        wv[r] = __builtin_amdgcn_exp2f(raw * kC);
      }
      *reinterpret_cast<f32x4*>(rp + m * 16) = wv;  // normal cached store
    }
  }
}

}  // namespace

extern "C" void kernel_launch(void* const* d_in, const int* in_sizes, int n_in,
                              void* d_out, int out_size, void* d_ws, size_t ws_size,
                              hipStream_t stream) {
  const float* emb = (const float*)d_in[1];  // d_in[0] = adj_in (unused by reference)
  float* out = (float*)d_out;

  // ws layout: [0, 16KB) reduction partials; coordT @16KB (2 MB); sq after.
  float* part = (float*)d_ws;
  unsigned short* coordT = (unsigned short*)((char*)d_ws + 16384);
  float* sq = (float*)((char*)d_ws + 16384 + (size_t)kB * kN * kF * sizeof(unsigned short));

  k_reduce1<<<1024, 256, 0, stream>>>(emb, part);
  k_convert<<<(kB * kN) / 64, 256, 0, stream>>>(emb, part, coordT, sq);
  dim3 grid(kN / 64, kN / 128, kB);
  k_gemm_exp<<<grid, 256, 0, stream>>>(coordT, sq, out);
}

// Round 9
// 77.403 us; speedup vs baseline: 1.1652x; 1.1652x over previous
//
#include <hip/hip_runtime.h>
#include <hip/hip_bf16.h>

namespace {

constexpr int kB = 4, kF = 64, kN = 4096;
constexpr int kM = kB * kF * kN;  // 1048576 total elements for std()

typedef __attribute__((ext_vector_type(8))) short bf16x8;
typedef __attribute__((ext_vector_type(4))) float f32x4;

__device__ __forceinline__ void wave_red2(float& s, float& q) {
#pragma unroll
  for (int o = 32; o > 0; o >>= 1) {
    s += __shfl_down(s, o, 64);
    q += __shfl_down(q, o, 64);
  }
}

// K1: 1024 blocks x 256 threads, each thread reduces 4 floats (float4 load).
__global__ void k_reduce1(const float* __restrict__ emb, float* __restrict__ part) {
  int t = blockIdx.x * blockDim.x + threadIdx.x;
  float4 v = reinterpret_cast<const float4*>(emb)[t];
  float s = v.x + v.y + v.z + v.w;
  float q = v.x * v.x + v.y * v.y + v.z * v.z + v.w * v.w;
  wave_red2(s, q);
  __shared__ float ls[4], lq[4];
  int lane = threadIdx.x & 63, w = threadIdx.x >> 6;
  if (lane == 0) { ls[w] = s; lq[w] = q; }
  __syncthreads();
  if (threadIdx.x == 0) {
    s = ls[0] + ls[1] + ls[2] + ls[3];
    q = lq[0] + lq[1] + lq[2] + lq[3];
    part[blockIdx.x] = s;
    part[1024 + blockIdx.x] = q;
  }
}

// K2: 256 blocks x 256 threads. Each block folds the 2048 partials itself
// (8 KB, L2-hit) -> inv_std, then converts 64 n-values: thread = (fq, nl).
// coordT[b][n][f] = bf16(emb[b][f][n] * inv_std); sq[b][n] = sum_f coord^2
// (sq from ROUNDED bf16 values so the diagonal of d2 is exactly 0).
__global__ __launch_bounds__(256) void k_convert(const float* __restrict__ emb,
                                                 const float* __restrict__ part,
                                                 unsigned short* __restrict__ coordT,
                                                 float* __restrict__ sq) {
  int t = threadIdx.x;
  float s = part[t] + part[t + 256] + part[t + 512] + part[t + 768];
  float q = part[1024 + t] + part[1280 + t] + part[1536 + t] + part[1792 + t];
  wave_red2(s, q);
  __shared__ float ls[4], lq[4];
  __shared__ float s_inv;
  int lane = t & 63, w = t >> 6;
  if (lane == 0) { ls[w] = s; lq[w] = q; }
  __syncthreads();
  if (t == 0) {
    s = ls[0] + ls[1] + ls[2] + ls[3];
    q = lq[0] + lq[1] + lq[2] + lq[3];
    float mean = s / (float)kM;
    float var = (q - s * mean) / (float)(kM - 1);  // Bessel ddof=1
    s_inv = 1.0f / sqrtf(var);
  }
  __syncthreads();
  float inv_std = s_inv;

  int nl = t & 63, fq = t >> 6;           // wave w == fq -> coalesced 256B loads
  int g = blockIdx.x * 64 + nl;           // [0, B*N)
  int b = g >> 12, n = g & 4095;
  const float* src = emb + ((size_t)b * kF + fq * 16) * kN + n;
  alignas(16) unsigned short loc[16];
  float acc = 0.f;
#pragma unroll
  for (int f = 0; f < 16; f++) {
    float v = src[(size_t)f * kN] * inv_std;
    union { __hip_bfloat16 h; unsigned short u; } cv;
    cv.h = __float2bfloat16(v);
    loc[f] = cv.u;
    float vf = __bfloat162float(cv.h);
    acc += vf * vf;
  }
  bf16x8* dst = reinterpret_cast<bf16x8*>(coordT + (size_t)g * kF + fq * 16);
  dst[0] = reinterpret_cast<const bf16x8*>(loc)[0];
  dst[1] = reinterpret_cast<const bf16x8*>(loc)[1];

  __shared__ float pacc[4][64];
  pacc[fq][nl] = acc;
  __syncthreads();
  if (fq == 0) sq[g] = pacc[0][nl] + pacc[1][nl] + pacc[2][nl] + pacc[3][nl];
}

// K3: out[y][x] = exp(-max(sq_x + sq_y - 2<c_x,c_y>, 0)/128)  (symmetric d2,
// so writing the (x,y) value at location (y,x) matches the reference).
// Block output tile: 64 rows (y) x 256 cols (x). 4 waves; wave w computes
// x-range [w*64, w*64+64) for all 64 y (32 MFMAs, same as R6).
// KEY CHANGE vs R6/R7: epilogue goes to LDS, then each wave streams 16 rows
// out with ONE 1KB-contiguous global_store_dwordx4 wave-instr per row.
// Theory: prior direct stores covered only 64B of each 128B L2 line per
// instr -> write-allocate fetched the line from HBM (RMW), ~doubling HBM
// traffic (R6 ~65us gemm vs 39us pure-write floor). Full-line stores kill
// the fetch. LDS pitch 260 floats (16B-aligned, even bank spread).
__global__ __launch_bounds__(256, 2) void k_gemm_exp(const unsigned short* __restrict__ coordT,
                                                     const float* __restrict__ sq,
                                                     float* __restrict__ out) {
  constexpr int kPitch = 260;  // floats per LDS row (256 + 4 pad)
  __shared__ float lds[64 * kPitch];  // 66.56 KB -> 2 blocks/CU

  int b = blockIdx.z;
  int wid = threadIdx.x >> 6;
  int lane = threadIdx.x & 63;
  int lhi = lane >> 4, llo = lane & 15;
  int y0 = blockIdx.x * 64;         // output rows (the "j" side)
  int x0 = blockIdx.y * 256;        // output cols (the "i" side)
  int xw = x0 + wid * 64;           // this wave's x-range
  const unsigned short* base = coordT + (size_t)b * kN * kF;

  // A fragments from x-rows, B fragments from y-rows (contig short8 per lane)
  bf16x8 af[4][2], bfr[4][2];
#pragma unroll
  for (int m = 0; m < 4; m++) {
    const unsigned short* p = base + (size_t)(xw + m * 16 + llo) * kF + lhi * 8;
    af[m][0] = *reinterpret_cast<const bf16x8*>(p);
    af[m][1] = *reinterpret_cast<const bf16x8*>(p + 32);
  }
#pragma unroll
  for (int n = 0; n < 4; n++) {
    const unsigned short* p = base + (size_t)(y0 + n * 16 + llo) * kF + lhi * 8;
    bfr[n][0] = *reinterpret_cast<const bf16x8*>(p);
    bfr[n][1] = *reinterpret_cast<const bf16x8*>(p + 32);
  }

  f32x4 acc[4][4] = {};
#pragma unroll
  for (int kk = 0; kk < 2; kk++)
#pragma unroll
    for (int m = 0; m < 4; m++)
#pragma unroll
      for (int n = 0; n < 4; n++)
        acc[m][n] = __builtin_amdgcn_mfma_f32_16x16x32_bf16(af[m][kk], bfr[n][kk], acc[m][n], 0, 0, 0);

  const float* sqb = sq + (size_t)b * kN;
  float si[4][4];
#pragma unroll
  for (int m = 0; m < 4; m++) {
    f32x4 tv = *reinterpret_cast<const f32x4*>(&sqb[xw + m * 16 + lhi * 4]);
    si[m][0] = tv[0]; si[m][1] = tv[1]; si[m][2] = tv[2]; si[m][3] = tv[3];
  }
  float sj[4];
#pragma unroll
  for (int n = 0; n < 4; n++) sj[n] = sqb[y0 + n * 16 + llo];

  // exp(-max(raw,0)/64/2) = exp2(-max(raw,0) * log2(e)/128)
  constexpr float kC = -0.011271055f;  // 1.4426950408889634 / 128
#pragma unroll
  for (int m = 0; m < 4; m++) {
#pragma unroll
    for (int n = 0; n < 4; n++) {
      f32x4 wv;
#pragma unroll
      for (int r = 0; r < 4; r++) {
        // acc layout: x = xw + m*16 + lhi*4 + r, y = y0 + n*16 + llo
        float raw = si[m][r] + sj[n] - 2.0f * acc[m][n][r];
        raw = fmaxf(raw, 0.0f);
        wv[r] = __builtin_amdgcn_exp2f(raw * kC);
      }
      int yloc = n * 16 + llo;
      int xloc = wid * 64 + m * 16 + lhi * 4;
      *reinterpret_cast<f32x4*>(&lds[yloc * kPitch + xloc]) = wv;
    }
  }
  __syncthreads();

  // Store phase: wave w streams rows [w*16, w*16+16); each row = one
  // 1KB-contiguous wave store (64 lanes x 16B), fully covering 8 x 128B lines.
  float* ob = out + (size_t)b * kN * kN + (size_t)y0 * kN + x0;
#pragma unroll
  for (int p = 0; p < 16; p++) {
    int yloc = wid * 16 + p;
    f32x4 v = *reinterpret_cast<const f32x4*>(&lds[yloc * kPitch + lane * 4]);
    *reinterpret_cast<f32x4*>(ob + (size_t)yloc * kN + lane * 4) = v;
  }
}

}  // namespace

extern "C" void kernel_launch(void* const* d_in, const int* in_sizes, int n_in,
                              void* d_out, int out_size, void* d_ws, size_t ws_size,
                              hipStream_t stream) {
  const float* emb = (const float*)d_in[1];  // d_in[0] = adj_in (unused by reference)
  float* out = (float*)d_out;

  // ws layout: [0, 16KB) reduction partials; coordT @16KB (2 MB); sq after.
  float* part = (float*)d_ws;
  unsigned short* coordT = (unsigned short*)((char*)d_ws + 16384);
  float* sq = (float*)((char*)d_ws + 16384 + (size_t)kB * kN * kF * sizeof(unsigned short));

  k_reduce1<<<1024, 256, 0, stream>>>(emb, part);
  k_convert<<<(kB * kN) / 64, 256, 0, stream>>>(emb, part, coordT, sq);
  dim3 grid(kN / 64, kN / 256, kB);
  k_gemm_exp<<<grid, 256, 0, stream>>>(coordT, sq, out);
}

// Round 10
// 69.969 us; speedup vs baseline: 1.2890x; 1.1062x over previous
//
#include <hip/hip_runtime.h>
#include <hip/hip_bf16.h>

namespace {

constexpr int kB = 4, kF = 64, kN = 4096;
constexpr int kM = kB * kF * kN;  // 1048576 total elements for std()

typedef __attribute__((ext_vector_type(8))) short bf16x8;
typedef __attribute__((ext_vector_type(4))) float f32x4;

__device__ __forceinline__ void wave_red2(float& s, float& q) {
#pragma unroll
  for (int o = 32; o > 0; o >>= 1) {
    s += __shfl_down(s, o, 64);
    q += __shfl_down(q, o, 64);
  }
}

// K1: 1024 blocks x 256 threads, each thread reduces 4 floats (float4 load).
__global__ void k_reduce1(const float* __restrict__ emb, float* __restrict__ part) {
  int t = blockIdx.x * blockDim.x + threadIdx.x;
  float4 v = reinterpret_cast<const float4*>(emb)[t];
  float s = v.x + v.y + v.z + v.w;
  float q = v.x * v.x + v.y * v.y + v.z * v.z + v.w * v.w;
  wave_red2(s, q);
  __shared__ float ls[4], lq[4];
  int lane = threadIdx.x & 63, w = threadIdx.x >> 6;
  if (lane == 0) { ls[w] = s; lq[w] = q; }
  __syncthreads();
  if (threadIdx.x == 0) {
    s = ls[0] + ls[1] + ls[2] + ls[3];
    q = lq[0] + lq[1] + lq[2] + lq[3];
    part[blockIdx.x] = s;
    part[1024 + blockIdx.x] = q;
  }
}

// K2: 256 blocks x 256 threads. Each block folds the 2048 partials itself
// (8 KB, L2-hit) -> inv_std, then converts 64 n-values: thread = (fq, nl).
// coordT[b][n][f] = bf16(emb[b][f][n] * inv_std); sq[b][n] = sum_f coord^2
// (sq from ROUNDED bf16 values so the diagonal of d2 is exactly 0).
__global__ __launch_bounds__(256) void k_convert(const float* __restrict__ emb,
                                                 const float* __restrict__ part,
                                                 unsigned short* __restrict__ coordT,
                                                 float* __restrict__ sq) {
  int t = threadIdx.x;
  float s = part[t] + part[t + 256] + part[t + 512] + part[t + 768];
  float q = part[1024 + t] + part[1280 + t] + part[1536 + t] + part[1792 + t];
  wave_red2(s, q);
  __shared__ float ls[4], lq[4];
  __shared__ float s_inv;
  int lane = t & 63, w = t >> 6;
  if (lane == 0) { ls[w] = s; lq[w] = q; }
  __syncthreads();
  if (t == 0) {
    s = ls[0] + ls[1] + ls[2] + ls[3];
    q = lq[0] + lq[1] + lq[2] + lq[3];
    float mean = s / (float)kM;
    float var = (q - s * mean) / (float)(kM - 1);  // Bessel ddof=1
    s_inv = 1.0f / sqrtf(var);
  }
  __syncthreads();
  float inv_std = s_inv;

  int nl = t & 63, fq = t >> 6;           // wave w == fq -> coalesced 256B loads
  int g = blockIdx.x * 64 + nl;           // [0, B*N)
  int b = g >> 12, n = g & 4095;
  const float* src = emb + ((size_t)b * kF + fq * 16) * kN + n;
  alignas(16) unsigned short loc[16];
  float acc = 0.f;
#pragma unroll
  for (int f = 0; f < 16; f++) {
    float v = src[(size_t)f * kN] * inv_std;
    union { __hip_bfloat16 h; unsigned short u; } cv;
    cv.h = __float2bfloat16(v);
    loc[f] = cv.u;
    float vf = __bfloat162float(cv.h);
    acc += vf * vf;
  }
  bf16x8* dst = reinterpret_cast<bf16x8*>(coordT + (size_t)g * kF + fq * 16);
  dst[0] = reinterpret_cast<const bf16x8*>(loc)[0];
  dst[1] = reinterpret_cast<const bf16x8*>(loc)[1];

  __shared__ float pacc[4][64];
  pacc[fq][nl] = acc;
  __syncthreads();
  if (fq == 0) sq[g] = pacc[0][nl] + pacc[1][nl] + pacc[2][nl] + pacc[3][nl];
}

// K3: out[y][x] = exp(-max(sq_x + sq_y - 2<c_x,c_y>, 0)/128)  (symmetric d2,
// so writing the (x,y) value at location (y,x) matches the reference).
// Block output tile: 64 rows (y) x 256 cols (x); LDS-staged epilogue with
// 1KB-contiguous wave stores (R9 — store-instr pattern proven irrelevant).
// R10 CHANGE: grid axes swapped so blockIdx.x -> x0 (fastest). Consecutive
// blocks now cover one contiguous 1 MiB row-band (16 blocks/band) instead of
// a buffer-wide column strip; the ~512 resident blocks touch ~32 contiguous
// MiB. Theory: write BW was DRAM-page-locality-bound (fills stream linearly
// at 6.8 TB/s; our scattered strips got ~4; R7's sparser scatter got worse).
__global__ __launch_bounds__(256, 2) void k_gemm_exp(const unsigned short* __restrict__ coordT,
                                                     const float* __restrict__ sq,
                                                     float* __restrict__ out) {
  constexpr int kPitch = 260;  // floats per LDS row (256 + 4 pad)
  __shared__ float lds[64 * kPitch];  // 66.56 KB -> 2 blocks/CU

  int b = blockIdx.z;
  int wid = threadIdx.x >> 6;
  int lane = threadIdx.x & 63;
  int lhi = lane >> 4, llo = lane & 15;
  int y0 = blockIdx.y * 64;         // output rows (the "j" side)
  int x0 = blockIdx.x * 256;        // output cols (the "i" side) — FASTEST
  int xw = x0 + wid * 64;           // this wave's x-range
  const unsigned short* base = coordT + (size_t)b * kN * kF;

  // A fragments from x-rows, B fragments from y-rows (contig short8 per lane)
  bf16x8 af[4][2], bfr[4][2];
#pragma unroll
  for (int m = 0; m < 4; m++) {
    const unsigned short* p = base + (size_t)(xw + m * 16 + llo) * kF + lhi * 8;
    af[m][0] = *reinterpret_cast<const bf16x8*>(p);
    af[m][1] = *reinterpret_cast<const bf16x8*>(p + 32);
  }
#pragma unroll
  for (int n = 0; n < 4; n++) {
    const unsigned short* p = base + (size_t)(y0 + n * 16 + llo) * kF + lhi * 8;
    bfr[n][0] = *reinterpret_cast<const bf16x8*>(p);
    bfr[n][1] = *reinterpret_cast<const bf16x8*>(p + 32);
  }

  f32x4 acc[4][4] = {};
#pragma unroll
  for (int kk = 0; kk < 2; kk++)
#pragma unroll
    for (int m = 0; m < 4; m++)
#pragma unroll
      for (int n = 0; n < 4; n++)
        acc[m][n] = __builtin_amdgcn_mfma_f32_16x16x32_bf16(af[m][kk], bfr[n][kk], acc[m][n], 0, 0, 0);

  const float* sqb = sq + (size_t)b * kN;
  float si[4][4];
#pragma unroll
  for (int m = 0; m < 4; m++) {
    f32x4 tv = *reinterpret_cast<const f32x4*>(&sqb[xw + m * 16 + lhi * 4]);
    si[m][0] = tv[0]; si[m][1] = tv[1]; si[m][2] = tv[2]; si[m][3] = tv[3];
  }
  float sj[4];
#pragma unroll
  for (int n = 0; n < 4; n++) sj[n] = sqb[y0 + n * 16 + llo];

  // exp(-max(raw,0)/64/2) = exp2(-max(raw,0) * log2(e)/128)
  constexpr float kC = -0.011271055f;  // 1.4426950408889634 / 128
#pragma unroll
  for (int m = 0; m < 4; m++) {
#pragma unroll
    for (int n = 0; n < 4; n++) {
      f32x4 wv;
#pragma unroll
      for (int r = 0; r < 4; r++) {
        // acc layout: x = xw + m*16 + lhi*4 + r, y = y0 + n*16 + llo
        float raw = si[m][r] + sj[n] - 2.0f * acc[m][n][r];
        raw = fmaxf(raw, 0.0f);
        wv[r] = __builtin_amdgcn_exp2f(raw * kC);
      }
      int yloc = n * 16 + llo;
      int xloc = wid * 64 + m * 16 + lhi * 4;
      *reinterpret_cast<f32x4*>(&lds[yloc * kPitch + xloc]) = wv;
    }
  }
  __syncthreads();

  // Store phase: wave w streams rows [w*16, w*16+16); each row = one
  // 1KB-contiguous wave store (64 lanes x 16B), fully covering 8 x 128B lines.
  float* ob = out + (size_t)b * kN * kN + (size_t)y0 * kN + x0;
#pragma unroll
  for (int p = 0; p < 16; p++) {
    int yloc = wid * 16 + p;
    f32x4 v = *reinterpret_cast<const f32x4*>(&lds[yloc * kPitch + lane * 4]);
    *reinterpret_cast<f32x4*>(ob + (size_t)yloc * kN + lane * 4) = v;
  }
}

}  // namespace

extern "C" void kernel_launch(void* const* d_in, const int* in_sizes, int n_in,
                              void* d_out, int out_size, void* d_ws, size_t ws_size,
                              hipStream_t stream) {
  const float* emb = (const float*)d_in[1];  // d_in[0] = adj_in (unused by reference)
  float* out = (float*)d_out;

  // ws layout: [0, 16KB) reduction partials; coordT @16KB (2 MB); sq after.
  float* part = (float*)d_ws;
  unsigned short* coordT = (unsigned short*)((char*)d_ws + 16384);
  float* sq = (float*)((char*)d_ws + 16384 + (size_t)kB * kN * kF * sizeof(unsigned short));

  k_reduce1<<<1024, 256, 0, stream>>>(emb, part);
  k_convert<<<(kB * kN) / 64, 256, 0, stream>>>(emb, part, coordT, sq);
  dim3 grid(kN / 256, kN / 64, kB);  // x (columns) fastest -> contiguous bands
  k_gemm_exp<<<grid, 256, 0, stream>>>(coordT, sq, out);
}